// Round 5
// baseline (583.464 us; speedup 1.0000x reference)
//
#include <hip/hip_runtime.h>
#include <cstdint>

// ============================================================================
// CEM policy (reference has the "buggy" gather sel[i,b] = actions[i, Is[i,b]],
// with Is < 64 indexing the ENV axis -> shared 6x64x32 tables per iteration).
//
// Plan:
//   P1: S_pre[8192][128] = state @ W1[0:64]             (candidate-invariant,
//       NO bias -- reference adds b1 after the full K=96 dot)
//   P2: W1aT[128][32] transpose of W1[64:96]; T_0 = eps_0(i<6, e<64, k);
//       meanW=0, stdW=1 for envs 0..63
//   A (x3, it=0..2): simulate envs 0..63 one iteration -> writes T_{it+1}
//   B: all 8192 envs, 4 iterations fused in one kernel (no grid sync needed:
//      cross-env coupling only flows through the precomputed T tables).
//
// RNG: JAX threefry2x32, PARTITIONABLE counter mode (default since JAX
//      0.4.36): element at flat index f (row-major over (64,8192,32)) gets
//      block tf20(key, x0=(f>>32)=0, x1=f); 32-bit draw combines the two
//      output words per PARTW below. fold_in is the raw cipher (unaffected).
//      uniform->normal matches XLA: bits>>9 | 1.0f, -1, *2 + lo, max(lo,.),
//      sqrt(2)*erfinv via Giles poly; log1p small path is a SELECT.
//
// PARTW: 0 -> o0^o1   (primary hypothesis for 32-bit partitionable draws)
//        1 -> o0      (fallback A)
//        2 -> o1      (fallback B)
//
// Round-3 result (original split-counter mode): absmax 11.77 -> that mode is
// ruled out (its implementation was re-audited correct).
//
// Rounding model (matches Tensile/XLA-CPU sequential-k accumulation):
//   layer1 h = (((0 fma state k=0..63) fma action k=0..31) + b1), relu
//   layer2 q = (sequential fma chain j=0..127 from 0) + b2
//   actions  = mean + std*eps  (separate mul/add, no contraction)
//   stats    = sequential adds, ddof=1 (ss/5)
//
// ws layout (floats): S_pre 1048576 | W1aT 4096 | T 4*12288 | meanW 2048 |
//                     stdW 2048  => ~4.42 MB required.
// ============================================================================

#define PARTW 0

#define TF_C 0x1BD11BDAu

__host__ __device__ __forceinline__ void tf20(uint32_t ks0, uint32_t ks1,
                                              uint32_t x0, uint32_t x1,
                                              uint32_t& o0, uint32_t& o1) {
  uint32_t ks2 = ks0 ^ ks1 ^ TF_C;
  x0 += ks0; x1 += ks1;
#define TF_RND(r) { x0 += x1; x1 = (x1 << (r)) | (x1 >> (32 - (r))); x1 ^= x0; }
  TF_RND(13) TF_RND(15) TF_RND(26) TF_RND(6)
  x0 += ks1; x1 += ks2 + 1u;
  TF_RND(17) TF_RND(29) TF_RND(16) TF_RND(24)
  x0 += ks2; x1 += ks0 + 2u;
  TF_RND(13) TF_RND(15) TF_RND(26) TF_RND(6)
  x0 += ks0; x1 += ks1 + 3u;
  TF_RND(17) TF_RND(29) TF_RND(16) TF_RND(24)
  x0 += ks1; x1 += ks2 + 4u;
  TF_RND(13) TF_RND(15) TF_RND(26) TF_RND(6)
  x0 += ks2; x1 += ks0 + 5u;
#undef TF_RND
  o0 = x0; o1 = x1;
}

// partitionable 32-bit draw for flat element index f (< 2^32 here, hi word 0)
__host__ __device__ __forceinline__ uint32_t pbits(uint32_t k0, uint32_t k1,
                                                   uint32_t f) {
  uint32_t o0, o1;
  tf20(k0, k1, 0u, f, o0, o1);
#if PARTW == 0
  return o0 ^ o1;
#elif PARTW == 1
  return o0;
#else
  return o1;
#endif
}

// bits -> N(0,1) sample, matching XLA bit-for-bit.
__device__ __forceinline__ float eps_from_bits(uint32_t bits) {
#pragma clang fp contract(off)
  const float LO = __uint_as_float(0xbf7fffffu);  // nextafter(-1, 0)
  float f = __uint_as_float((bits >> 9) | 0x3f800000u) - 1.0f;  // [0,1)
  float u = fmaxf(LO, f * 2.0f + LO);  // (hi-lo) rounds to exactly 2.0f
  float t = -(u * u);
  // XLA EmitLog1p: Select(|t|<1e-4, t*(1 - t/2), log(1+t)) -- both evaluated.
  float w_large = logf(t + 1.0f);
  float w_small = ((-0.5f * t) + 1.0f) * t;
  float w = (fabsf(t) < 1e-4f) ? w_small : w_large;
  w = -w;
  float p;
  if (w < 5.0f) {
    float ww = w - 2.5f;
    p = 2.81022636e-08f;
    p = 3.43273939e-07f + p * ww;
    p = -3.5233877e-06f + p * ww;
    p = -4.39150654e-06f + p * ww;
    p = 0.00021858087f + p * ww;
    p = -0.00125372503f + p * ww;
    p = -0.00417768164f + p * ww;
    p = 0.246640727f + p * ww;
    p = 1.50140941f + p * ww;
  } else {
    float ww = sqrtf(w) - 3.0f;
    p = -0.000200214257f;
    p = 0.000100950558f + p * ww;
    p = 0.00134934322f + p * ww;
    p = -0.00367342844f + p * ww;
    p = 0.00573950773f + p * ww;
    p = -0.0076224613f + p * ww;
    p = 0.00943887047f + p * ww;
    p = 1.00167406f + p * ww;
    p = 2.83297682f + p * ww;
  }
  float r = p * u;
  return __uint_as_float(0x3fb504f3u) * r;  // float32(sqrt(2)) * erfinv(u)
}

// lane = candidate c in [0,64). eps[k] = eps(c, env, k); flat index
// f = c*2^18 + env*32 + k over shape (64, 8192, 32). Fully lane-local.
__device__ __forceinline__ void gen_eps(uint32_t k0, uint32_t k1, int env,
                                        int lane, float eps[32]) {
  const uint32_t base = (uint32_t)lane * 262144u + (uint32_t)env * 32u;
#pragma unroll
  for (int k = 0; k < 32; ++k)
    eps[k] = eps_from_bits(pbits(k0, k1, base + (uint32_t)k));
}

// Q(state_b, a). Layer1: continue S_pre's fma chain with the 32 action terms,
// then + b1 (HLO order), relu. Layer2: fma chain from 0, + b2 last.
// Srow/W1aT/b1/W2 wave-uniform -> s_load + v_fmac v,s,v expected.
__device__ __forceinline__ float qeval(const float* __restrict__ Srow,
                                       const float* __restrict__ W1aT,
                                       const float* __restrict__ b1,
                                       const float* __restrict__ W2,
                                       float b2v, const float a[32]) {
  float q = 0.0f;
#pragma unroll 4
  for (int j = 0; j < 128; ++j) {
    float h = Srow[j];
    const float* wr = W1aT + j * 32;
#pragma unroll
    for (int k = 0; k < 32; ++k) h = __builtin_fmaf(a[k], wr[k], h);
    h = h + b1[j];
    h = fmaxf(h, 0.0f);
    q = __builtin_fmaf(h, W2[j], q);
  }
  return q + b2v;
}

// iterative wave argmax: value desc, index asc (matches lax.top_k ordering).
__device__ __forceinline__ void top6(float q, int lane, int top[6]) {
  float qv = q;
#pragma unroll
  for (int i = 0; i < 6; ++i) {
    float v = qv;
    int idx = lane;
#pragma unroll
    for (int off = 1; off < 64; off <<= 1) {
      float ov = __shfl_xor(v, off, 64);
      int oi = __shfl_xor(idx, off, 64);
      if (ov > v || (ov == v && oi < idx)) { v = ov; idx = oi; }
    }
    top[i] = __builtin_amdgcn_readfirstlane(idx);
    if (lane == idx) qv = -__builtin_inff();
  }
}

// mean (div 6) and ddof=1 std (div 5), sequential order, no fma.
__device__ __forceinline__ void stats6(const float sel[6], float& mean, float& sd) {
#pragma clang fp contract(off)
  float s = ((((sel[0] + sel[1]) + sel[2]) + sel[3]) + sel[4]) + sel[5];
  mean = s / 6.0f;
  float d0 = sel[0] - mean, d1 = sel[1] - mean, d2 = sel[2] - mean;
  float d3 = sel[3] - mean, d4 = sel[4] - mean, d5 = sel[5] - mean;
  float p0 = d0 * d0, p1 = d1 * d1, p2 = d2 * d2;
  float p3 = d3 * d3, p4 = d4 * d4, p5 = d5 * d5;
  float ss = ((((p0 + p1) + p2) + p3) + p4) + p5;
  sd = sqrtf(ss / 5.0f);
}

__device__ __forceinline__ float rdlane(float v, int l) {
  return __int_as_float(__builtin_amdgcn_readlane(__float_as_int(v), l));
}

// ---------------------------------------------------------------------------
__global__ void __launch_bounds__(128) k_prep_spre(const float* __restrict__ state,
                                                   const float* __restrict__ W1,
                                                   float* __restrict__ S_pre) {
  const int b = blockIdx.x;   // 8192
  const int j = threadIdx.x;  // 128
  float h = 0.0f;             // bias added later, after the action part
  const float* srow = state + (size_t)b * 64;
#pragma unroll 8
  for (int k = 0; k < 64; ++k) h = __builtin_fmaf(srow[k], W1[k * 128 + j], h);
  S_pre[(size_t)b * 128 + j] = h;
}

__global__ void __launch_bounds__(256) k_prep_misc(const float* __restrict__ W1,
                                                   float* __restrict__ W1aT,
                                                   float* __restrict__ T0,
                                                   float* __restrict__ meanW,
                                                   float* __restrict__ stdW,
                                                   uint32_t K0, uint32_t K1) {
  const int tid = blockIdx.x * 256 + threadIdx.x;  // 12288 threads
  if (tid < 4096) {  // W1aT[j][k] = W1[64+k][j]
    int j = tid >> 5, k = tid & 31;
    W1aT[tid] = W1[(64 + k) * 128 + j];
  }
  {  // T0[i][e][k] = eps_0(i,e,k)  (mean=0, std=1 -> exact)
    int i = tid >> 11, rem = tid & 2047;  // rem = e*32+k
    uint32_t f = (uint32_t)i * 262144u + (uint32_t)rem;
    T0[tid] = eps_from_bits(pbits(K0, K1, f));
  }
  if (tid < 2048) { meanW[tid] = 0.0f; stdW[tid] = 1.0f; }
}

// one CEM iteration for envs 0..63; produces T_{it+1}. grid 16 x 256.
__global__ void __launch_bounds__(256) k_stage1(const float* __restrict__ S_pre,
    const float* __restrict__ W1aT, const float* __restrict__ b1,
    const float* __restrict__ W2, const float* __restrict__ b2,
    const float* __restrict__ Tcur, float* __restrict__ Tnext,
    float* __restrict__ meanW, float* __restrict__ stdW, uint32_t K0,
    uint32_t K1, uint32_t NK0, uint32_t NK1) {
  const int lane = threadIdx.x & 63;
  const int e = __builtin_amdgcn_readfirstlane((int)(blockIdx.x * 4 + (threadIdx.x >> 6)));
  const int kk = lane & 31;
  float eps[32];
  gen_eps(K0, K1, e, lane, eps);
  float a[32];
  {
#pragma clang fp contract(off)
#pragma unroll
    for (int k = 0; k < 32; ++k) {
      float mk = meanW[e * 32 + k];
      float sk = stdW[e * 32 + k];
      a[k] = mk + sk * eps[k];
    }
  }
  float q = qeval(S_pre + (size_t)e * 128, W1aT, b1, W2, b2[0], a);
  int top[6];
  top6(q, lane, top);
  float sel[6];
#pragma unroll
  for (int i = 0; i < 6; ++i) sel[i] = Tcur[(size_t)((i * 64 + top[i]) * 32) + kk];
  float vmean, vsd;
  stats6(sel, vmean, vsd);
  if (lane < 32) {
    meanW[e * 32 + kk] = vmean;
    stdW[e * 32 + kk] = vsd;
  }
  // T_{it+1}[i][e][k] = mean_new[k] + std_new[k] * eps_{it+1}(i,e,k), i<6
#pragma unroll
  for (int t = 0; t < 3; ++t) {
    int m = lane * 3 + t;  // 0..191
    int i = m >> 5, k = m & 31;
    uint32_t f = (uint32_t)i * 262144u + (uint32_t)e * 32u + (uint32_t)k;
    float ev = eps_from_bits(pbits(NK0, NK1, f));
    float mk = __shfl(vmean, k, 64);
    float sk = __shfl(vsd, k, 64);
    float val;
    {
#pragma clang fp contract(off)
      val = mk + sk * ev;
    }
    Tnext[(size_t)((i * 64 + e) * 32 + k)] = val;
  }
}

// all 8192 envs, 4 fused iterations. grid 2048 x 256 (wave = env).
// mean/std live lane-sliced in 2 VGPRs (vmean/vsd); materialized into a[]
// via v_readlane (compile-time lane index -> no scratch).
__global__ void __launch_bounds__(256) k_main(const float* __restrict__ S_pre,
    const float* __restrict__ W1aT, const float* __restrict__ b1,
    const float* __restrict__ W2, const float* __restrict__ b2,
    const float* __restrict__ T, float* __restrict__ out, uint4 kx, uint4 ky) {
  const int lane = threadIdx.x & 63;
  const int b = __builtin_amdgcn_readfirstlane((int)(blockIdx.x * 4 + (threadIdx.x >> 6)));
  const float* Srow = S_pre + (size_t)b * 128;
  const float bb2 = b2[0];
  const int kk = lane & 31;
  float vmean = 0.0f, vsd = 1.0f;
  for (int it = 0; it < 4; ++it) {
    uint32_t K0 = it == 0 ? kx.x : it == 1 ? kx.y : it == 2 ? kx.z : kx.w;
    uint32_t K1 = it == 0 ? ky.x : it == 1 ? ky.y : it == 2 ? ky.z : ky.w;
    float eps[32];
    gen_eps(K0, K1, b, lane, eps);
    float a[32];
    if (it == 0) {
      // mean=0, std=1: a = 0 + 1*eps = eps bitwise.
#pragma unroll
      for (int k = 0; k < 32; ++k) a[k] = eps[k];
    } else {
#pragma clang fp contract(off)
#pragma unroll
      for (int k = 0; k < 32; ++k) {
        float mk = rdlane(vmean, k);
        float sk = rdlane(vsd, k);
        a[k] = mk + sk * eps[k];
      }
    }
    float q = qeval(Srow, W1aT, b1, W2, bb2, a);
    int top[6];
    top6(q, lane, top);
    const float* Tt = T + it * 12288;
    float sel0 = Tt[(size_t)(top[0] * 32) + kk];
    if (it == 3) {
      if (lane < 32) out[(size_t)b * 32 + kk] = sel0;
    } else {
      float sel[6];
      sel[0] = sel0;
#pragma unroll
      for (int i = 1; i < 6; ++i) sel[i] = Tt[(size_t)((i * 64 + top[i]) * 32) + kk];
      stats6(sel, vmean, vsd);
    }
  }
}

// ---------------------------------------------------------------------------
extern "C" void kernel_launch(void* const* d_in, const int* in_sizes, int n_in,
                              void* d_out, int out_size, void* d_ws,
                              size_t ws_size, hipStream_t stream) {
  const float* state = (const float*)d_in[0];  // 8192*64
  const float* W1 = (const float*)d_in[1];     // 96*128
  const float* b1 = (const float*)d_in[2];     // 128
  const float* W2 = (const float*)d_in[3];     // 128
  const float* b2 = (const float*)d_in[4];     // 1
  float* out = (float*)d_out;                  // 8192*32

  float* ws = (float*)d_ws;
  float* S_pre = ws;                    // 1,048,576 floats
  float* W1aT = ws + 1048576;           // 4,096
  float* T = W1aT + 4096;               // 4 * 12,288
  float* meanW = T + 4 * 12288;         // 2,048
  float* stdW = meanW + 2048;           // 2,048  (total ~4.42 MB)

  // fold_in(key(42), it) = threefry cipher block (k=(0,42), x=(0,it)) --
  // raw cipher, NOT random_bits: unaffected by the partitionable flag.
  uint32_t K0[4], K1[4];
  for (uint32_t i = 0; i < 4; ++i) {
    uint32_t a, bb;
    tf20(0u, 42u, 0u, i, a, bb);
    K0[i] = a;
    K1[i] = bb;
  }

  k_prep_spre<<<8192, 128, 0, stream>>>(state, W1, S_pre);
  k_prep_misc<<<48, 256, 0, stream>>>(W1, W1aT, T, meanW, stdW, K0[0], K1[0]);
  for (int it = 0; it < 3; ++it)
    k_stage1<<<16, 256, 0, stream>>>(S_pre, W1aT, b1, W2, b2, T + it * 12288,
                                     T + (it + 1) * 12288, meanW, stdW, K0[it],
                                     K1[it], K0[it + 1], K1[it + 1]);
  k_main<<<2048, 256, 0, stream>>>(S_pre, W1aT, b1, W2, b2, T, out,
                                   make_uint4(K0[0], K0[1], K0[2], K0[3]),
                                   make_uint4(K1[0], K1[1], K1[2], K1[3]));
}